// Round 1
// baseline (760.781 us; speedup 1.0000x reference)
//
#include <hip/hip_runtime.h>

// Problem constants (fixed by the reference):
constexpr int Bn = 8;     // batch
constexpr int En = 8;     // experts
constexpr int Cn = 1024;  // capacity
constexpr int In = 128;   // in features (K)
constexpr int On = 256;   // out features (N)
constexpr int Tn = 8192;  // num tokens

constexpr int BM = 64;    // token tile
constexpr int BN = 64;    // output tile
constexpr int BK = 64;    // K tile (2 iterations over In=128)

// ---------------------------------------------------------------------------
// Zero-fill d_out (B*T*O floats). Harness poisons d_out to 0xAA each call.
// ---------------------------------------------------------------------------
__global__ void zero_out_kernel(float4* __restrict__ p, int n4) {
    int i = blockIdx.x * blockDim.x + threadIdx.x;
    int stride = gridDim.x * blockDim.x;
    for (; i < n4; i += stride) p[i] = float4{0.f, 0.f, 0.f, 0.f};
}

// ---------------------------------------------------------------------------
// Fused per-expert GEMM + bias + gate + scatter-add.
// Block tile: BM x BN, 256 threads (16x16), each thread 4x4 micro-tile.
// LDS: A and B tiles stored [row][k] as float4 chunks with XOR swizzle
//   slot = ck ^ ((row>>2) & 7)
// -> A reads (4 rows broadcast across 16 lanes) and B reads (16 distinct
//    rows) are both bank-conflict-free (<=2-way, free per m136).
// ---------------------------------------------------------------------------
__global__ __launch_bounds__(256, 4)
void moe_gemm_scatter(const float* __restrict__ x,      // (B,E,C,I)
                      const int*   __restrict__ idx,    // (B,E,C)
                      const float* __restrict__ gate,   // (B,E,C)
                      const float* __restrict__ w,      // (E,O,I)
                      const float* __restrict__ bias,   // (O)
                      float* __restrict__ out)          // (B,T,O)
{
    __shared__ float4 As4[BM * (BK / 4)];  // 64 rows x 16 chunks = 16 KB
    __shared__ float4 Bs4[BN * (BK / 4)];  // 16 KB

    const int bid = blockIdx.x;
    const int oT = bid & 3;          // 4 output tiles
    const int cT = (bid >> 2) & 15;  // 16 capacity tiles
    const int e  = (bid >> 6) & 7;
    const int b  = bid >> 9;

    const int tid = threadIdx.x;
    const int tx = tid & 15;   // output micro-tile index (n = oT*64 + 4*tx + j)
    const int ty = tid >> 4;   // token  micro-tile index (c = cT*64 + 4*ty + i)

    const float* xbase = x + (((size_t)b * En + e) * Cn + (size_t)cT * BM) * In;
    const float* wbase = w + ((size_t)e * On + (size_t)oT * BN) * In;

    float acc[4][4] = {};

    for (int k0 = 0; k0 < In; k0 += BK) {
        // ---- stage A (x tile) and B (weight tile) into LDS, swizzled ----
        #pragma unroll
        for (int it = 0; it < 4; ++it) {
            int f4  = tid + 256 * it;   // 0..1023
            int row = f4 >> 4;          // 0..63
            int ck  = f4 & 15;          // float4 chunk within row
            float4 av = *(const float4*)(xbase + (size_t)row * In + k0 + 4 * ck);
            float4 bv = *(const float4*)(wbase + (size_t)row * In + k0 + 4 * ck);
            int slot = row * 16 + (ck ^ ((row >> 2) & 7));
            As4[slot] = av;
            Bs4[slot] = bv;
        }
        __syncthreads();

        // ---- 4x4 micro-tile FMA over this K tile ----
        #pragma unroll
        for (int kk = 0; kk < BK / 4; ++kk) {
            float4 a[4], bb[4];
            #pragma unroll
            for (int i = 0; i < 4; ++i) {
                int m = 4 * ty + i;
                a[i] = As4[m * 16 + (kk ^ ((m >> 2) & 7))];
            }
            #pragma unroll
            for (int j = 0; j < 4; ++j) {
                int n = 4 * tx + j;
                bb[j] = Bs4[n * 16 + (kk ^ ((n >> 2) & 7))];
            }
            #pragma unroll
            for (int i = 0; i < 4; ++i) {
                #pragma unroll
                for (int j = 0; j < 4; ++j) {
                    acc[i][j] += a[i].x * bb[j].x + a[i].y * bb[j].y +
                                 a[i].z * bb[j].z + a[i].w * bb[j].w;
                }
            }
        }
        __syncthreads();
    }

    // ---- epilogue: (acc + bias) * gate, scatter-add into out[b][t][n] ----
    const int n0g = oT * BN;
    const size_t ig_base = ((size_t)b * En + e) * Cn + (size_t)cT * BM;
    const float4 bias4 = *(const float4*)(bias + n0g + 4 * tx);
    float* outb = out + (size_t)b * Tn * On;

    #pragma unroll
    for (int i = 0; i < 4; ++i) {
        int c = 4 * ty + i;
        int t = idx[ig_base + c];
        float g = gate[ig_base + c];
        float* op = outb + (size_t)t * On + n0g + 4 * tx;
        atomicAdd(op + 0, (acc[i][0] + bias4.x) * g);
        atomicAdd(op + 1, (acc[i][1] + bias4.y) * g);
        atomicAdd(op + 2, (acc[i][2] + bias4.z) * g);
        atomicAdd(op + 3, (acc[i][3] + bias4.w) * g);
    }
}

extern "C" void kernel_launch(void* const* d_in, const int* in_sizes, int n_in,
                              void* d_out, int out_size, void* d_ws, size_t ws_size,
                              hipStream_t stream) {
    const float* x    = (const float*)d_in[0];  // (B,E,C,I) fp32
    const int*   idx  = (const int*)  d_in[1];  // (B,E,C) int32
    const float* gate = (const float*)d_in[2];  // (B,E,C) fp32
    const float* w    = (const float*)d_in[3];  // (E,O,I) fp32
    const float* bias = (const float*)d_in[4];  // (O,) fp32
    // d_in[5] = num_tokens scalar (T=8192, hardcoded)
    float* out = (float*)d_out;

    const int n4 = (Bn * Tn * On) / 4;  // 4,194,304 float4s
    zero_out_kernel<<<4096, 256, 0, stream>>>((float4*)out, n4);

    const int nblocks = Bn * En * (Cn / BM) * (On / BN);  // 4096
    moe_gemm_scatter<<<nblocks, 256, 0, stream>>>(x, idx, gate, w, bias, out);
}